// Round 11
// baseline (2474.442 us; speedup 1.0000x reference)
//
#include <hip/hip_runtime.h>
#include <hip/hip_bf16.h>
#include <stdint.h>

// B=8, S=1024, D=512, H=8, DK=512 (H*DK=4096).
// CONTRACT (decoded r0-5): inputs fp32, OUTPUT fp32, ws = 256 MiB exactly.
// R20 = R19 + flash_attn: combine the two proven wins that were never
// combined — 8-wave blocks (R16: halved staging per q-row) x 2 blocks/CU
// (R13/R14: cross-block staging-latency hiding). Single-buffered Ks/Vs,
// R13's 3-barrier schedule, LDS 74.5KB -> 16 waves/CU (4/SIMD, 2x all prior
// flash configs). DMA patterns byte-identical (n=2 V rule).
// qkv(R19 256x128)/fc(R16)/cvt/layernorm unchanged.
typedef __attribute__((ext_vector_type(8))) short short8;
typedef __attribute__((ext_vector_type(4))) float f32x4;

__device__ __forceinline__ short f2bf(float f) {
  __hip_bfloat16 h = __float2bfloat16(f);
  union { __hip_bfloat16 h; short s; } x;
  x.h = h;
  return x.s;
}
// async global->LDS, 16B/lane; lds ptr must equal wave-uniform base + lane*16
__device__ __forceinline__ void g2lds16(const void* g, void* l) {
  __builtin_amdgcn_global_load_lds(
      (const __attribute__((address_space(1))) void*)g,
      (__attribute__((address_space(3))) void*)l, 16, 0, 0);
}

// ---------------------------------------------------------------------------
// K0a: fp32 -> bf16 pre-convert for qkv inputs+weights (one launch, z picks).
// ---------------------------------------------------------------------------
__global__ void cvt6(const float* __restrict__ q, const float* __restrict__ k,
                     const float* __restrict__ v, const float* __restrict__ wq,
                     const float* __restrict__ wk, const float* __restrict__ wv,
                     short* __restrict__ xb, short* __restrict__ wb)
{
  const int z = blockIdx.z;
  const float* s;
  short* d;
  long nvec;
  if (z < 3) { s = (z == 0) ? q : (z == 1) ? k : v;  d = xb + (long)z * 4194304; nvec = 524288; }
  else       { s = (z == 3) ? wq : (z == 4) ? wk : wv; d = wb + (long)(z - 3) * 2097152; nvec = 262144; }
  const long stride = (long)gridDim.x * blockDim.x;
  for (long i = (long)blockIdx.x * blockDim.x + threadIdx.x; i < nvec; i += stride) {
    f32x4 a = *(const f32x4*)(s + i * 8);
    f32x4 b = *(const f32x4*)(s + i * 8 + 4);
    short8 o;
#pragma unroll
    for (int t = 0; t < 4; ++t) { o[t] = f2bf(a[t]); o[4 + t] = f2bf(b[t]); }
    *(short8*)(d + i * 8) = o;
  }
}

// K0b: single-array fp32->bf16 (for wfc, launched after attn).
__global__ void cvt1(const float* __restrict__ s, short* __restrict__ d, int nvec)
{
  const long stride = (long)gridDim.x * blockDim.x;
  for (long i = (long)blockIdx.x * blockDim.x + threadIdx.x; i < nvec; i += stride) {
    f32x4 a = *(const f32x4*)(s + i * 8);
    f32x4 b = *(const f32x4*)(s + i * 8 + 4);
    short8 o;
#pragma unroll
    for (int t = 0; t < 4; ++t) { o[t] = f2bf(a[t]); o[4 + t] = f2bf(b[t]); }
    *(short8*)(d + i * 8) = o;
  }
}

// ---------------------------------------------------------------------------
// K1: QKV projection (R19) — 256x128 tile, 8 waves, BK=32 dbuf prefetch.
// M=8192, N=4096, K=512. z=0/1 -> (B,H,S,DK); z=2 (V) -> (B,H,DK,S).
// ---------------------------------------------------------------------------
__global__ __launch_bounds__(512) void qkv_proj(
    const short* __restrict__ xb, const short* __restrict__ wb,
    short* __restrict__ Qh, short* __restrict__ Kh, short* __restrict__ Vt)
{
  __shared__ __align__(16) short As[2][256 * 32];  // 2 x 16 KB
  __shared__ __align__(16) short Bs[2][128 * 32];  // 2 x 8 KB
  const int z = blockIdx.z;
  const short* x = xb + (long)z * 4194304;
  const short* W = wb + (long)z * 2097152;
  short* out = (z == 0) ? Qh : (z == 1) ? Kh : Vt;
  const int tid = threadIdx.x;
  const int wave = tid >> 6, lane = tid & 63;
  const int quad = lane >> 4, l15 = lane & 15;
  const int mBase = blockIdx.x * 256, nBase = blockIdx.y * 128;
  const int wm = wave >> 1, wn = wave & 1;
  f32x4 acc[4][4] = {};

  auto stage = [&](int kk, int b_) {
#pragma unroll
    for (int i = 0; i < 2; ++i) {               // A: 256x32 = 1024 chunks
      int c = i * 512 + tid;
      int r = c >> 2, o = (c & 3) * 8;
      g2lds16(x + (long)(mBase + r) * 512 + kk + o, (char*)(As[b_]) + c * 16);
    }
    {                                           // B: 128x32 = 512 chunks
      int c = tid;
      int r = c >> 2, o = (c & 3) * 8;
      g2lds16(W + (long)(nBase + r) * 512 + kk + o, (char*)(Bs[b_]) + c * 16);
    }
  };
  stage(0, 0);

  for (int it = 0; it < 16; ++it) {
    const int buf = it & 1;
    stage(((it + 1) & 15) * 32, buf ^ 1);  // wrap at it=15: harmless refill
    __builtin_amdgcn_sched_barrier(0);
    asm volatile("s_waitcnt vmcnt(3)" ::: "memory");  // tile it's 3 DMAs done
    __builtin_amdgcn_s_barrier();
    __builtin_amdgcn_sched_barrier(0);
    short8 a[4], b[4];
#pragma unroll
    for (int mi = 0; mi < 4; ++mi)
      a[mi] = *(const short8*)(As[buf] + (wm * 64 + mi * 16 + l15) * 32 + quad * 8);
#pragma unroll
    for (int ni = 0; ni < 4; ++ni)
      b[ni] = *(const short8*)(Bs[buf] + (wn * 64 + ni * 16 + l15) * 32 + quad * 8);
#pragma unroll
    for (int mi = 0; mi < 4; ++mi)
#pragma unroll
      for (int ni = 0; ni < 4; ++ni)
        acc[mi][ni] = __builtin_amdgcn_mfma_f32_16x16x32_bf16(a[mi], b[ni], acc[mi][ni], 0, 0, 0);
    __builtin_amdgcn_s_barrier();  // B_end: buf reads done before next overwrite
    __builtin_amdgcn_sched_barrier(0);
  }
  asm volatile("s_waitcnt vmcnt(0)" ::: "memory");  // retire wrap DMAs

#pragma unroll
  for (int mi = 0; mi < 4; ++mi) {
#pragma unroll
    for (int ni = 0; ni < 4; ++ni) {
      int n = nBase + wn * 64 + ni * 16 + l15;
      int h = n >> 9, d = n & 511;
#pragma unroll
      for (int r = 0; r < 4; ++r) {
        int m = mBase + wm * 64 + mi * 16 + quad * 4 + r;
        int b = m >> 10, s = m & 1023;
        long idx;
        if (z == 2) idx = ((long)(b * 8 + h) * 512 + d) * 1024 + s;   // V: (B,H,DK,S)
        else        idx = ((long)(b * 8 + h) * 1024 + s) * 512 + d;   // (B,H,S,DK)
        out[idx] = f2bf(acc[mi][ni][r]);
      }
    }
  }
}

// ---------------------------------------------------------------------------
// K2: flash attention v7 — 8 waves, 128 q-rows/block, SINGLE-buffered Ks/Vs,
// 2 blocks/CU (16 waves/CU): co-resident block hides staging latency
// (R13/R14 mechanism) while 8-wave halves staging per q-row (R16 mechanism).
//  - Ks XOR-swizzled (r*64+(j^(r&7))); Vs XOR-swizzled (d*4+(j^(d&3))).
//  - Iter: B0 sync [prior reads done] -> stageK(kt), stageV(kt) ->
//    B1 vmcnt(4) [K landed; V's 4 in flight under QK^T] ->
//    QK^T + softmax -> Ps -> B2 syncthreads [full drain: V landed, Ps vis]
//    -> vf<-Vs once -> PV (8 q-groups x own 64-d slice).
//  - Grid 512; XCD swizzle: qt=(lin>>3)&7, bh=((lin>>6)<<3)|(lin&7).
// ---------------------------------------------------------------------------
__global__ __launch_bounds__(512, 4) void flash_attn(
    const short* __restrict__ Qh, const short* __restrict__ Kh,
    const short* __restrict__ Vt, short* __restrict__ ctx)
{
  __shared__ __align__(16) short Ks[32 * 512];     // 32 KB
  __shared__ __align__(16) short Vs[512 * 32];     // 32 KB
  __shared__ __align__(16) short Ps[8 * 16 * 40];  // 10 KB padded rows
  __shared__ float lred[128];
  const int tid = threadIdx.x;
  const int wave = tid >> 6, lane = tid & 63;
  const int quad = lane >> 4, l15 = lane & 15;
  const int lin = blockIdx.x;
  const int qt = (lin >> 3) & 7;
  const int bh = ((lin >> 6) << 3) | (lin & 7);
  const float C = 0.0637587234f;  // log2(e)/sqrt(512)

  // Q fragments: wave's 16 q-rows (A-operand: A[m=l15][k=quad*8+j])
  const short* qbase = Qh + ((long)bh * 1024 + qt * 128 + wave * 16 + l15) * 512 + quad * 8;
  short8 qf[16];
#pragma unroll
  for (int c = 0; c < 16; ++c) qf[c] = *(const short8*)(qbase + c * 32);

  f32x4 acc[8][4] = {};               // O: [q-group g][d-tile of wave's 64-d slice]
  float l[4] = {0.f, 0.f, 0.f, 0.f};  // lane-local partial denominators (own rows)

  for (int kt = 0; kt < 32; ++kt) {
    __syncthreads();  // B0: prior iter's Ks/Vs/Ps reads done before overwrite
#pragma unroll
    for (int i = 0; i < 4; ++i) {     // K tile: 2048 chunks, 4/thread
      int c = i * 512 + tid;
      int r = c >> 6, j = (c & 63) ^ (r & 7);
      g2lds16(Kh + ((long)bh * 1024 + kt * 32 + r) * 512 + j * 8, (char*)Ks + c * 16);
    }
    __builtin_amdgcn_sched_barrier(0);  // pin issue order: K DMAs before V DMAs
#pragma unroll
    for (int i = 0; i < 4; ++i) {     // V tile: 2048 chunks, 4/thread
      int c = i * 512 + tid;
      int d = c >> 2, j = (c & 3) ^ (d & 3);
      g2lds16(Vt + ((long)bh * 512 + d) * 1024 + kt * 32 + j * 8, (char*)Vs + c * 16);
    }
    __builtin_amdgcn_sched_barrier(0);
    // B1: K's 4 DMAs done (V's 4 in flight, hidden under QK^T)
    asm volatile("s_waitcnt vmcnt(4)" ::: "memory");
    __builtin_amdgcn_s_barrier();
    __builtin_amdgcn_sched_barrier(0);

    // S = Q K^T : own 16 q-rows x 32 keys
    f32x4 sacc[2] = {};
    __builtin_amdgcn_s_setprio(1);
#pragma unroll
    for (int nt = 0; nt < 2; ++nt)
#pragma unroll
      for (int c = 0; c < 16; ++c) {
        int row = nt * 16 + l15;
        int j = (c * 4 + quad) ^ (row & 7);
        short8 kf = *(const short8*)(Ks + row * 512 + j * 8);
        sacc[nt] = __builtin_amdgcn_mfma_f32_16x16x32_bf16(qf[c], kf, sacc[nt], 0, 0, 0);
      }
    __builtin_amdgcn_s_setprio(0);
    // p = exp2(s*C); lane-local partial sums; P into padded LDS
#pragma unroll
    for (int r = 0; r < 4; ++r) {
      float p0 = exp2f(sacc[0][r] * C);
      float p1 = exp2f(sacc[1][r] * C);
      Ps[wave * 640 + (quad * 4 + r) * 40 + l15]      = f2bf(p0);
      Ps[wave * 640 + (quad * 4 + r) * 40 + 16 + l15] = f2bf(p1);
      l[r] += p0 + p1;
    }
    __syncthreads();  // B2: full drain (V landed; Ps visible; lockstep)

    // V fragments for wave's 64-d slice: read ONCE, reuse across 8 g
    short8 vf[4];
#pragma unroll
    for (int t = 0; t < 4; ++t) {
      int row = wave * 64 + t * 16 + l15;
      int j = quad ^ (row & 3);
      vf[t] = *(const short8*)(Vs + row * 32 + j * 8);
    }
    // O += P V : all 8 q-groups x wave's 64-d slice
    __builtin_amdgcn_s_setprio(1);
#pragma unroll
    for (int g = 0; g < 8; ++g) {
      short8 pf = *(const short8*)(Ps + g * 640 + l15 * 40 + quad * 8);
#pragma unroll
      for (int t = 0; t < 4; ++t)
        acc[g][t] = __builtin_amdgcn_mfma_f32_16x16x32_bf16(pf, vf[t], acc[g][t], 0, 0, 0);
    }
    __builtin_amdgcn_s_setprio(0);
  }
  // deferred denominator reduction (within each quad's 16 lanes)
#pragma unroll
  for (int r = 0; r < 4; ++r) {
    float t = l[r];
    t += __shfl_xor(t, 1);
    t += __shfl_xor(t, 2);
    t += __shfl_xor(t, 4);
    t += __shfl_xor(t, 8);
    l[r] = t;
  }
  if (l15 == 0) {
#pragma unroll
    for (int r = 0; r < 4; ++r) lred[wave * 16 + quad * 4 + r] = l[r];
  }
  __syncthreads();
  // epilogue: /l, store ctx (B,S,H*DK), wave's 64-d slice for all 8 q-groups
  const int b = bh >> 3, h = bh & 7;
#pragma unroll
  for (int g = 0; g < 8; ++g) {
#pragma unroll
    for (int r = 0; r < 4; ++r) {
      float inv = 1.0f / lred[g * 16 + quad * 4 + r];
      int qrow = qt * 128 + g * 16 + quad * 4 + r;
      long base = ((long)(b * 1024 + qrow)) * 4096 + h * 512 + wave * 64;
#pragma unroll
      for (int t = 0; t < 4; ++t)
        ctx[base + t * 16 + l15] = f2bf(acc[g][t][r] * inv);
    }
  }
}

// ---------------------------------------------------------------------------
// K3: fc + residual, dbuf prefetch (R16). M=8192, N=512, K=4096.
// 128x64 tiles, grid (64,8) = 512 blocks. Per wave 64x32: acc[4][2].
// ---------------------------------------------------------------------------
__global__ void fc_gemm(
    const short* __restrict__ A, const short* __restrict__ Wb,
    const float* __restrict__ resid, float* __restrict__ Y)
{
  __shared__ __align__(16) short As[2][128 * 32];
  __shared__ __align__(16) short Bs[2][64 * 32];
  const int tid = threadIdx.x;
  const int wave = tid >> 6, lane = tid & 63;
  const int quad = lane >> 4, l15 = lane & 15;
  const int mBase = blockIdx.x * 128, nBase = blockIdx.y * 64;
  const int wm = wave >> 1, wn = wave & 1;
  const int c0 = tid, c1 = tid + 256;
  const int r0 = c0 >> 2, o0 = (c0 & 3) * 8;
  const int r1 = c1 >> 2, o1 = (c1 & 3) * 8;
  f32x4 acc[4][2] = {};

  auto stage = [&](int kk, int b_) {
    g2lds16(A + (long)(mBase + r0) * 4096 + kk + o0, (char*)(As[b_]) + c0 * 16);
    g2lds16(A + (long)(mBase + r1) * 4096 + kk + o1, (char*)(As[b_]) + c1 * 16);
    g2lds16(Wb + (long)(nBase + r0) * 4096 + kk + o0, (char*)(Bs[b_]) + c0 * 16);
  };
  stage(0, 0);

  for (int it = 0; it < 128; ++it) {
    const int buf = it & 1;
    stage(((it + 1) & 127) * 32, buf ^ 1);  // wrap at it=127: harmless refill
    __builtin_amdgcn_sched_barrier(0);
    asm volatile("s_waitcnt vmcnt(3)" ::: "memory");  // tile it's 3 DMAs done
    __builtin_amdgcn_s_barrier();
    __builtin_amdgcn_sched_barrier(0);
    short8 a[4], b[2];
#pragma unroll
    for (int mi = 0; mi < 4; ++mi)
      a[mi] = *(const short8*)(As[buf] + (wm * 64 + mi * 16 + l15) * 32 + quad * 8);
#pragma unroll
    for (int ni = 0; ni < 2; ++ni)
      b[ni] = *(const short8*)(Bs[buf] + (wn * 32 + ni * 16 + l15) * 32 + quad * 8);
#pragma unroll
    for (int mi = 0; mi < 4; ++mi)
#pragma unroll
      for (int ni = 0; ni < 2; ++ni)
        acc[mi][ni] = __builtin_amdgcn_mfma_f32_16x16x32_bf16(a[mi], b[ni], acc[mi][ni], 0, 0, 0);
    __builtin_amdgcn_s_barrier();  // B_end
    __builtin_amdgcn_sched_barrier(0);
  }
  asm volatile("s_waitcnt vmcnt(0)" ::: "memory");  // retire wrap DMAs

#pragma unroll
  for (int mi = 0; mi < 4; ++mi)
#pragma unroll
    for (int ni = 0; ni < 2; ++ni) {
      int n = nBase + wn * 32 + ni * 16 + l15;
#pragma unroll
      for (int r = 0; r < 4; ++r) {
        int m = mBase + wm * 64 + mi * 16 + quad * 4 + r;
        long idx = (long)m * 512 + n;
        Y[idx] = acc[mi][ni][r] + resid[idx];
      }
    }
}

// ---------------------------------------------------------------------------
// K4: LayerNorm (unchanged).
// ---------------------------------------------------------------------------
__global__ void layernorm(
    const float* __restrict__ Y, const float* __restrict__ gamma,
    const float* __restrict__ beta, float* __restrict__ out)
{
  const int tid = threadIdx.x;
  const int wave = tid >> 6, lane = tid & 63;
  const long row = (long)blockIdx.x * 4 + wave;
  f32x4 xa = *(const f32x4*)(Y + row * 512 + lane * 8);
  f32x4 xb = *(const f32x4*)(Y + row * 512 + lane * 8 + 4);
  float x[8];
  float s = 0.f, s2 = 0.f;
#pragma unroll
  for (int i = 0; i < 4; ++i) { x[i] = xa[i]; x[i + 4] = xb[i]; }
#pragma unroll
  for (int i = 0; i < 8; ++i) { s += x[i]; s2 += x[i] * x[i]; }
#pragma unroll
  for (int m = 1; m < 64; m <<= 1) { s += __shfl_xor(s, m); s2 += __shfl_xor(s2, m); }
  float mu = s * (1.0f / 512.0f);
  float var = s2 * (1.0f / 512.0f) - mu * mu;
  float rs = rsqrtf(var + 1e-6f);
  f32x4 oa, ob;
#pragma unroll
  for (int i = 0; i < 4; ++i) {
    oa[i] = (x[i] - mu) * rs * gamma[lane * 8 + i] + beta[lane * 8 + i];
    ob[i] = (x[i + 4] - mu) * rs * gamma[lane * 8 + 4 + i] + beta[lane * 8 + 4 + i];
  }
  *(f32x4*)(out + row * 512 + lane * 8) = oa;
  *(f32x4*)(out + row * 512 + lane * 8 + 4) = ob;
}

extern "C" void kernel_launch(void* const* d_in, const int* in_sizes, int n_in,
                              void* d_out, int out_size, void* d_ws, size_t ws_size,
                              hipStream_t stream) {
  const float* q     = (const float*)d_in[0];
  const float* k     = (const float*)d_in[1];
  const float* v     = (const float*)d_in[2];
  const float* wq    = (const float*)d_in[3];
  const float* wk    = (const float*)d_in[4];
  const float* wv    = (const float*)d_in[5];
  const float* wfc   = (const float*)d_in[6];
  const float* gamma = (const float*)d_in[7];
  const float* beta  = (const float*)d_in[8];
  float* out = (float*)d_out;
  char* ws = (char*)d_ws;
  short* Qh  = (short*)(ws);                    // [0,64M)   bf16, dead after attn
  short* Kh  = (short*)(ws + 67108864);         // [64,128M)
  short* Vt  = (short*)(ws + 134217728);        // [128,192M)
  short* ctx = (short*)(ws + 201326592);        // [192,256M) attn out (bf16)
  // cvt6 outputs live in the ctx region BEFORE attn overwrites it:
  short* xb  = (short*)(ws + 201326592);        // q/k/v bf16: 3 x 8 MB
  short* wb  = xb + 3 * 4194304;                // wq/wk/wv bf16: 3 x 4 MB
  // wfc bf16 lives in the dead-Qh region AFTER attn (Y uses [0,16M) fp32):
  short* wfcb = (short*)(ws + 16777216);        // [16,20M)
  float* Y   = (float*)(ws);                    // fp32 [0,16M), aliases dead Qh

  cvt6<<<dim3(1024, 1, 6), 256, 0, stream>>>(q, k, v, wq, wk, wv, xb, wb);
  qkv_proj<<<dim3(32, 32, 3), 512, 0, stream>>>(xb, wb, Qh, Kh, Vt);
  flash_attn<<<dim3(512), 512, 0, stream>>>(Qh, Kh, Vt, ctx);
  cvt1<<<dim3(1024), 256, 0, stream>>>(wfc, wfcb, 262144);
  fc_gemm<<<dim3(64, 8), 256, 0, stream>>>(ctx, wfcb, q, Y);
  layernorm<<<2048, 256, 0, stream>>>(Y, gamma, beta, out);
}

// Round 12
// 649.513 us; speedup vs baseline: 3.8097x; 3.8097x over previous
//
#include <hip/hip_runtime.h>
#include <hip/hip_bf16.h>
#include <stdint.h>

// B=8, S=1024, D=512, H=8, DK=512 (H*DK=4096).
// CONTRACT (decoded r0-5): inputs fp32, OUTPUT fp32, ws = 256 MiB exactly.
// R21 = R19 verbatim (verified best: 637.5us).
// R20 lesson (terminal for the occupancy axis): flash per-wave state
// (acc[8][4]=128 AGPR + qf[16]=64 VGPR + misc) ~= 256 unified regs -> 2
// waves/SIMD is a hard ceiling; forcing 4/SIMD (launch_bounds 512,4) made the
// compiler spill to scratch (VGPR 64, 7.7GB spill traffic, 2037us).
// Axes closed by measurement: occupancy (R15/R20), sync structure (R17/R18),
// DMA latency (R15/R16), V-access pattern (R9/R12 n=2).
typedef __attribute__((ext_vector_type(8))) short short8;
typedef __attribute__((ext_vector_type(4))) float f32x4;

__device__ __forceinline__ short f2bf(float f) {
  __hip_bfloat16 h = __float2bfloat16(f);
  union { __hip_bfloat16 h; short s; } x;
  x.h = h;
  return x.s;
}
// async global->LDS, 16B/lane; lds ptr must equal wave-uniform base + lane*16
__device__ __forceinline__ void g2lds16(const void* g, void* l) {
  __builtin_amdgcn_global_load_lds(
      (const __attribute__((address_space(1))) void*)g,
      (__attribute__((address_space(3))) void*)l, 16, 0, 0);
}

// ---------------------------------------------------------------------------
// K0a: fp32 -> bf16 pre-convert for qkv inputs+weights (one launch, z picks).
// ---------------------------------------------------------------------------
__global__ void cvt6(const float* __restrict__ q, const float* __restrict__ k,
                     const float* __restrict__ v, const float* __restrict__ wq,
                     const float* __restrict__ wk, const float* __restrict__ wv,
                     short* __restrict__ xb, short* __restrict__ wb)
{
  const int z = blockIdx.z;
  const float* s;
  short* d;
  long nvec;
  if (z < 3) { s = (z == 0) ? q : (z == 1) ? k : v;  d = xb + (long)z * 4194304; nvec = 524288; }
  else       { s = (z == 3) ? wq : (z == 4) ? wk : wv; d = wb + (long)(z - 3) * 2097152; nvec = 262144; }
  const long stride = (long)gridDim.x * blockDim.x;
  for (long i = (long)blockIdx.x * blockDim.x + threadIdx.x; i < nvec; i += stride) {
    f32x4 a = *(const f32x4*)(s + i * 8);
    f32x4 b = *(const f32x4*)(s + i * 8 + 4);
    short8 o;
#pragma unroll
    for (int t = 0; t < 4; ++t) { o[t] = f2bf(a[t]); o[4 + t] = f2bf(b[t]); }
    *(short8*)(d + i * 8) = o;
  }
}

// K0b: single-array fp32->bf16 (for wfc, launched after attn).
__global__ void cvt1(const float* __restrict__ s, short* __restrict__ d, int nvec)
{
  const long stride = (long)gridDim.x * blockDim.x;
  for (long i = (long)blockIdx.x * blockDim.x + threadIdx.x; i < nvec; i += stride) {
    f32x4 a = *(const f32x4*)(s + i * 8);
    f32x4 b = *(const f32x4*)(s + i * 8 + 4);
    short8 o;
#pragma unroll
    for (int t = 0; t < 4; ++t) { o[t] = f2bf(a[t]); o[4 + t] = f2bf(b[t]); }
    *(short8*)(d + i * 8) = o;
  }
}

// ---------------------------------------------------------------------------
// K1: QKV projection — 256x128 tile, 8 waves (512 thr), BK=32 dbuf prefetch.
// M=8192, N=4096, K=512. z=0/1 -> (B,H,S,DK); z=2 (V) -> (B,H,DK,S).
// ---------------------------------------------------------------------------
__global__ __launch_bounds__(512) void qkv_proj(
    const short* __restrict__ xb, const short* __restrict__ wb,
    short* __restrict__ Qh, short* __restrict__ Kh, short* __restrict__ Vt)
{
  __shared__ __align__(16) short As[2][256 * 32];  // 2 x 16 KB
  __shared__ __align__(16) short Bs[2][128 * 32];  // 2 x 8 KB
  const int z = blockIdx.z;
  const short* x = xb + (long)z * 4194304;
  const short* W = wb + (long)z * 2097152;
  short* out = (z == 0) ? Qh : (z == 1) ? Kh : Vt;
  const int tid = threadIdx.x;
  const int wave = tid >> 6, lane = tid & 63;
  const int quad = lane >> 4, l15 = lane & 15;
  const int mBase = blockIdx.x * 256, nBase = blockIdx.y * 128;
  const int wm = wave >> 1, wn = wave & 1;
  f32x4 acc[4][4] = {};

  auto stage = [&](int kk, int b_) {
#pragma unroll
    for (int i = 0; i < 2; ++i) {               // A: 256x32 = 1024 chunks
      int c = i * 512 + tid;
      int r = c >> 2, o = (c & 3) * 8;
      g2lds16(x + (long)(mBase + r) * 512 + kk + o, (char*)(As[b_]) + c * 16);
    }
    {                                           // B: 128x32 = 512 chunks
      int c = tid;
      int r = c >> 2, o = (c & 3) * 8;
      g2lds16(W + (long)(nBase + r) * 512 + kk + o, (char*)(Bs[b_]) + c * 16);
    }
  };
  stage(0, 0);

  for (int it = 0; it < 16; ++it) {
    const int buf = it & 1;
    stage(((it + 1) & 15) * 32, buf ^ 1);  // wrap at it=15: harmless refill
    __builtin_amdgcn_sched_barrier(0);
    asm volatile("s_waitcnt vmcnt(3)" ::: "memory");  // tile it's 3 DMAs done
    __builtin_amdgcn_s_barrier();
    __builtin_amdgcn_sched_barrier(0);
    short8 a[4], b[4];
#pragma unroll
    for (int mi = 0; mi < 4; ++mi)
      a[mi] = *(const short8*)(As[buf] + (wm * 64 + mi * 16 + l15) * 32 + quad * 8);
#pragma unroll
    for (int ni = 0; ni < 4; ++ni)
      b[ni] = *(const short8*)(Bs[buf] + (wn * 64 + ni * 16 + l15) * 32 + quad * 8);
#pragma unroll
    for (int mi = 0; mi < 4; ++mi)
#pragma unroll
      for (int ni = 0; ni < 4; ++ni)
        acc[mi][ni] = __builtin_amdgcn_mfma_f32_16x16x32_bf16(a[mi], b[ni], acc[mi][ni], 0, 0, 0);
    __builtin_amdgcn_s_barrier();  // B_end: buf reads done before next overwrite
    __builtin_amdgcn_sched_barrier(0);
  }
  asm volatile("s_waitcnt vmcnt(0)" ::: "memory");  // retire wrap DMAs

#pragma unroll
  for (int mi = 0; mi < 4; ++mi) {
#pragma unroll
    for (int ni = 0; ni < 4; ++ni) {
      int n = nBase + wn * 64 + ni * 16 + l15;
      int h = n >> 9, d = n & 511;
#pragma unroll
      for (int r = 0; r < 4; ++r) {
        int m = mBase + wm * 64 + mi * 16 + quad * 4 + r;
        int b = m >> 10, s = m & 1023;
        long idx;
        if (z == 2) idx = ((long)(b * 8 + h) * 512 + d) * 1024 + s;   // V: (B,H,DK,S)
        else        idx = ((long)(b * 8 + h) * 1024 + s) * 512 + d;   // (B,H,S,DK)
        out[idx] = f2bf(acc[mi][ni][r]);
      }
    }
  }
}

// ---------------------------------------------------------------------------
// K2: flash attention — 8 waves, 128 q-rows/block, K dbuf (R16/R19 verbatim).
//  - Ks[2] XOR-swizzled (r*64+(j^(r&7))); Vs single, XOR-swizzled
//    (d*4+(j^(d&3))).
//  - Schedule/iter: stageK(kt+1)->Ks[buf^1]; stageV(kt)->Vs;
//    B1 vmcnt(8); QK^T + softmax -> Ps; B2 vmcnt(4) lgkmcnt(0);
//    vf<-Vs once, PV all 8 q-groups x own 64-d slice; B_end lgkmcnt(0).
//  - Grid 512; XCD swizzle: qt=(lin>>3)&7, bh=((lin>>6)<<3)|(lin&7).
// ---------------------------------------------------------------------------
__global__ __launch_bounds__(512, 2) void flash_attn(
    const short* __restrict__ Qh, const short* __restrict__ Kh,
    const short* __restrict__ Vt, short* __restrict__ ctx)
{
  __shared__ __align__(16) short Ks[2][32 * 512];  // 64 KB dbuf
  __shared__ __align__(16) short Vs[512 * 32];     // 32 KB
  __shared__ __align__(16) short Ps[8 * 16 * 40];  // 10 KB padded rows
  __shared__ float lred[128];
  const int tid = threadIdx.x;
  const int wave = tid >> 6, lane = tid & 63;
  const int quad = lane >> 4, l15 = lane & 15;
  const int lin = blockIdx.x;
  const int qt = (lin >> 3) & 7;
  const int bh = ((lin >> 6) << 3) | (lin & 7);
  const float C = 0.0637587234f;  // log2(e)/sqrt(512)

  // Q fragments: wave's 16 q-rows (A-operand: A[m=l15][k=quad*8+j])
  const short* qbase = Qh + ((long)bh * 1024 + qt * 128 + wave * 16 + l15) * 512 + quad * 8;
  short8 qf[16];
#pragma unroll
  for (int c = 0; c < 16; ++c) qf[c] = *(const short8*)(qbase + c * 32);

  auto stageK = [&](int kt_, int b_) {
#pragma unroll
    for (int i = 0; i < 4; ++i) {
      int c = i * 512 + tid;
      int r = c >> 6, j = (c & 63) ^ (r & 7);
      g2lds16(Kh + ((long)bh * 1024 + kt_ * 32 + r) * 512 + j * 8, (char*)(Ks[b_]) + c * 16);
    }
  };
  auto stageV = [&](int kt_) {
#pragma unroll
    for (int i = 0; i < 4; ++i) {
      int c = i * 512 + tid;
      int d = c >> 2, j = (c & 3) ^ (d & 3);
      g2lds16(Vt + ((long)bh * 512 + d) * 1024 + kt_ * 32 + j * 8, (char*)Vs + c * 16);
    }
  };
  stageK(0, 0);

  f32x4 acc[8][4] = {};               // O: [q-group g][d-tile of wave's 64-d slice]
  float l[4] = {0.f, 0.f, 0.f, 0.f};  // lane-local partial denominators (own rows)

  for (int kt = 0; kt < 32; ++kt) {
    const int buf = kt & 1;
    stageK((kt + 1) & 31, buf ^ 1);   // wrap at kt=31: harmless refill
    __builtin_amdgcn_sched_barrier(0);
    stageV(kt);
    __builtin_amdgcn_sched_barrier(0);
    // B1: K(kt) landed (K(kt+1) 4 + V(kt) 4 = 8 newer stay in flight)
    asm volatile("s_waitcnt vmcnt(8)" ::: "memory");
    __builtin_amdgcn_s_barrier();
    __builtin_amdgcn_sched_barrier(0);

    // S = Q K^T : own 16 q-rows x 32 keys
    const short* ks = Ks[buf];
    f32x4 sacc[2] = {};
#pragma unroll
    for (int nt = 0; nt < 2; ++nt)
#pragma unroll
      for (int c = 0; c < 16; ++c) {
        int row = nt * 16 + l15;
        int j = (c * 4 + quad) ^ (row & 7);
        short8 kf = *(const short8*)(ks + row * 512 + j * 8);
        sacc[nt] = __builtin_amdgcn_mfma_f32_16x16x32_bf16(qf[c], kf, sacc[nt], 0, 0, 0);
      }
    // p = exp2(s*C); lane-local partial sums; P into padded LDS
#pragma unroll
    for (int r = 0; r < 4; ++r) {
      float p0 = exp2f(sacc[0][r] * C);
      float p1 = exp2f(sacc[1][r] * C);
      Ps[wave * 640 + (quad * 4 + r) * 40 + l15]      = f2bf(p0);
      Ps[wave * 640 + (quad * 4 + r) * 40 + 16 + l15] = f2bf(p1);
      l[r] += p0 + p1;
    }
    // B2: V(kt) landed (K(kt+1) in flight); Ps visible; K reads drained
    asm volatile("s_waitcnt vmcnt(4) lgkmcnt(0)" ::: "memory");
    __builtin_amdgcn_s_barrier();
    __builtin_amdgcn_sched_barrier(0);

    // V fragments for wave's 64-d slice: read ONCE, reuse across 8 g
    short8 vf[4];
#pragma unroll
    for (int t = 0; t < 4; ++t) {
      int row = wave * 64 + t * 16 + l15;
      int j = quad ^ (row & 3);
      vf[t] = *(const short8*)(Vs + row * 32 + j * 8);
    }
    // O += P V : all 8 q-groups x wave's 64-d slice
#pragma unroll
    for (int g = 0; g < 8; ++g) {
      short8 pf = *(const short8*)(Ps + g * 640 + l15 * 40 + quad * 8);
#pragma unroll
      for (int t = 0; t < 4; ++t)
        acc[g][t] = __builtin_amdgcn_mfma_f32_16x16x32_bf16(pf, vf[t], acc[g][t], 0, 0, 0);
    }
    // B_end: this iter's LDS reads drained before next iter's DMA overwrite
    asm volatile("s_waitcnt lgkmcnt(0)" ::: "memory");
    __builtin_amdgcn_s_barrier();
    __builtin_amdgcn_sched_barrier(0);
  }
  // deferred denominator reduction (within each quad's 16 lanes)
#pragma unroll
  for (int r = 0; r < 4; ++r) {
    float t = l[r];
    t += __shfl_xor(t, 1);
    t += __shfl_xor(t, 2);
    t += __shfl_xor(t, 4);
    t += __shfl_xor(t, 8);
    l[r] = t;
  }
  if (l15 == 0) {
#pragma unroll
    for (int r = 0; r < 4; ++r) lred[wave * 16 + quad * 4 + r] = l[r];
  }
  __syncthreads();  // full drain: lred visible + wrap DMAs retired
  // epilogue: /l, store ctx (B,S,H*DK), wave's 64-d slice for all 8 q-groups
  const int b = bh >> 3, h = bh & 7;
#pragma unroll
  for (int g = 0; g < 8; ++g) {
#pragma unroll
    for (int r = 0; r < 4; ++r) {
      float inv = 1.0f / lred[g * 16 + quad * 4 + r];
      int qrow = qt * 128 + g * 16 + quad * 4 + r;
      long base = ((long)(b * 1024 + qrow)) * 4096 + h * 512 + wave * 64;
#pragma unroll
      for (int t = 0; t < 4; ++t)
        ctx[base + t * 16 + l15] = f2bf(acc[g][t][r] * inv);
    }
  }
}

// ---------------------------------------------------------------------------
// K3: fc + residual, dbuf prefetch. M=8192, N=512, K=4096.
// 128x64 tiles, grid (64,8) = 512 blocks. Per wave 64x32: acc[4][2].
// ---------------------------------------------------------------------------
__global__ void fc_gemm(
    const short* __restrict__ A, const short* __restrict__ Wb,
    const float* __restrict__ resid, float* __restrict__ Y)
{
  __shared__ __align__(16) short As[2][128 * 32];
  __shared__ __align__(16) short Bs[2][64 * 32];
  const int tid = threadIdx.x;
  const int wave = tid >> 6, lane = tid & 63;
  const int quad = lane >> 4, l15 = lane & 15;
  const int mBase = blockIdx.x * 128, nBase = blockIdx.y * 64;
  const int wm = wave >> 1, wn = wave & 1;
  const int c0 = tid, c1 = tid + 256;
  const int r0 = c0 >> 2, o0 = (c0 & 3) * 8;
  const int r1 = c1 >> 2, o1 = (c1 & 3) * 8;
  f32x4 acc[4][2] = {};

  auto stage = [&](int kk, int b_) {
    g2lds16(A + (long)(mBase + r0) * 4096 + kk + o0, (char*)(As[b_]) + c0 * 16);
    g2lds16(A + (long)(mBase + r1) * 4096 + kk + o1, (char*)(As[b_]) + c1 * 16);
    g2lds16(Wb + (long)(nBase + r0) * 4096 + kk + o0, (char*)(Bs[b_]) + c0 * 16);
  };
  stage(0, 0);

  for (int it = 0; it < 128; ++it) {
    const int buf = it & 1;
    stage(((it + 1) & 127) * 32, buf ^ 1);  // wrap at it=127: harmless refill
    __builtin_amdgcn_sched_barrier(0);
    asm volatile("s_waitcnt vmcnt(3)" ::: "memory");  // tile it's 3 DMAs done
    __builtin_amdgcn_s_barrier();
    __builtin_amdgcn_sched_barrier(0);
    short8 a[4], b[2];
#pragma unroll
    for (int mi = 0; mi < 4; ++mi)
      a[mi] = *(const short8*)(As[buf] + (wm * 64 + mi * 16 + l15) * 32 + quad * 8);
#pragma unroll
    for (int ni = 0; ni < 2; ++ni)
      b[ni] = *(const short8*)(Bs[buf] + (wn * 32 + ni * 16 + l15) * 32 + quad * 8);
#pragma unroll
    for (int mi = 0; mi < 4; ++mi)
#pragma unroll
      for (int ni = 0; ni < 2; ++ni)
        acc[mi][ni] = __builtin_amdgcn_mfma_f32_16x16x32_bf16(a[mi], b[ni], acc[mi][ni], 0, 0, 0);
    __builtin_amdgcn_s_barrier();  // B_end
    __builtin_amdgcn_sched_barrier(0);
  }
  asm volatile("s_waitcnt vmcnt(0)" ::: "memory");  // retire wrap DMAs

#pragma unroll
  for (int mi = 0; mi < 4; ++mi)
#pragma unroll
    for (int ni = 0; ni < 2; ++ni) {
      int n = nBase + wn * 32 + ni * 16 + l15;
#pragma unroll
      for (int r = 0; r < 4; ++r) {
        int m = mBase + wm * 64 + mi * 16 + quad * 4 + r;
        long idx = (long)m * 512 + n;
        Y[idx] = acc[mi][ni][r] + resid[idx];
      }
    }
}

// ---------------------------------------------------------------------------
// K4: LayerNorm (unchanged).
// ---------------------------------------------------------------------------
__global__ void layernorm(
    const float* __restrict__ Y, const float* __restrict__ gamma,
    const float* __restrict__ beta, float* __restrict__ out)
{
  const int tid = threadIdx.x;
  const int wave = tid >> 6, lane = tid & 63;
  const long row = (long)blockIdx.x * 4 + wave;
  f32x4 xa = *(const f32x4*)(Y + row * 512 + lane * 8);
  f32x4 xb = *(const f32x4*)(Y + row * 512 + lane * 8 + 4);
  float x[8];
  float s = 0.f, s2 = 0.f;
#pragma unroll
  for (int i = 0; i < 4; ++i) { x[i] = xa[i]; x[i + 4] = xb[i]; }
#pragma unroll
  for (int i = 0; i < 8; ++i) { s += x[i]; s2 += x[i] * x[i]; }
#pragma unroll
  for (int m = 1; m < 64; m <<= 1) { s += __shfl_xor(s, m); s2 += __shfl_xor(s2, m); }
  float mu = s * (1.0f / 512.0f);
  float var = s2 * (1.0f / 512.0f) - mu * mu;
  float rs = rsqrtf(var + 1e-6f);
  f32x4 oa, ob;
#pragma unroll
  for (int i = 0; i < 4; ++i) {
    oa[i] = (x[i] - mu) * rs * gamma[lane * 8 + i] + beta[lane * 8 + i];
    ob[i] = (x[i + 4] - mu) * rs * gamma[lane * 8 + 4 + i] + beta[lane * 8 + 4 + i];
  }
  *(f32x4*)(out + row * 512 + lane * 8) = oa;
  *(f32x4*)(out + row * 512 + lane * 8 + 4) = ob;
}

extern "C" void kernel_launch(void* const* d_in, const int* in_sizes, int n_in,
                              void* d_out, int out_size, void* d_ws, size_t ws_size,
                              hipStream_t stream) {
  const float* q     = (const float*)d_in[0];
  const float* k     = (const float*)d_in[1];
  const float* v     = (const float*)d_in[2];
  const float* wq    = (const float*)d_in[3];
  const float* wk    = (const float*)d_in[4];
  const float* wv    = (const float*)d_in[5];
  const float* wfc   = (const float*)d_in[6];
  const float* gamma = (const float*)d_in[7];
  const float* beta  = (const float*)d_in[8];
  float* out = (float*)d_out;
  char* ws = (char*)d_ws;
  short* Qh  = (short*)(ws);                    // [0,64M)   bf16, dead after attn
  short* Kh  = (short*)(ws + 67108864);         // [64,128M)
  short* Vt  = (short*)(ws + 134217728);        // [128,192M)
  short* ctx = (short*)(ws + 201326592);        // [192,256M) attn out (bf16)
  // cvt6 outputs live in the ctx region BEFORE attn overwrites it:
  short* xb  = (short*)(ws + 201326592);        // q/k/v bf16: 3 x 8 MB
  short* wb  = xb + 3 * 4194304;                // wq/wk/wv bf16: 3 x 4 MB
  // wfc bf16 lives in the dead-Qh region AFTER attn (Y uses [0,16M) fp32):
  short* wfcb = (short*)(ws + 16777216);        // [16,20M)
  float* Y   = (float*)(ws);                    // fp32 [0,16M), aliases dead Qh

  cvt6<<<dim3(1024, 1, 6), 256, 0, stream>>>(q, k, v, wq, wk, wv, xb, wb);
  qkv_proj<<<dim3(32, 32, 3), 512, 0, stream>>>(xb, wb, Qh, Kh, Vt);
  flash_attn<<<dim3(512), 512, 0, stream>>>(Qh, Kh, Vt, ctx);
  cvt1<<<dim3(1024), 256, 0, stream>>>(wfc, wfcb, 262144);
  fc_gemm<<<dim3(64, 8), 256, 0, stream>>>(ctx, wfcb, q, Y);
  layernorm<<<2048, 256, 0, stream>>>(Y, gamma, beta, out);
}

// Round 13
// 604.203 us; speedup vs baseline: 4.0954x; 1.0750x over previous
//
#include <hip/hip_runtime.h>
#include <hip/hip_bf16.h>
#include <stdint.h>

// B=8, S=1024, D=512, H=8, DK=512 (H*DK=4096).
// CONTRACT (decoded r0-5): inputs fp32, OUTPUT fp32, ws = 256 MiB exactly.
// R22 = R21 + ONE change: qkv_proj z=2 (V^T) epilogue stores coalesced via
// LDS transpose tile (VT[128][264] overlaid on dead staging LDS). Old path:
// 2B/lane at 2KB stride = 64 L2 transactions per store instr (partial-line
// RMW on the whole 64MB V^T tensor). New: row-wise 16B/lane, full 64B lines.
// Hazards: own-wave vmcnt(0) + syncthreads before VT overwrites staging;
// barrier between VT write/read. Everything else R21-verbatim (649.5us).
typedef __attribute__((ext_vector_type(8))) short short8;
typedef __attribute__((ext_vector_type(4))) float f32x4;

__device__ __forceinline__ short f2bf(float f) {
  __hip_bfloat16 h = __float2bfloat16(f);
  union { __hip_bfloat16 h; short s; } x;
  x.h = h;
  return x.s;
}
// async global->LDS, 16B/lane; lds ptr must equal wave-uniform base + lane*16
__device__ __forceinline__ void g2lds16(const void* g, void* l) {
  __builtin_amdgcn_global_load_lds(
      (const __attribute__((address_space(1))) void*)g,
      (__attribute__((address_space(3))) void*)l, 16, 0, 0);
}

// ---------------------------------------------------------------------------
// K0a: fp32 -> bf16 pre-convert for qkv inputs+weights (one launch, z picks).
// ---------------------------------------------------------------------------
__global__ void cvt6(const float* __restrict__ q, const float* __restrict__ k,
                     const float* __restrict__ v, const float* __restrict__ wq,
                     const float* __restrict__ wk, const float* __restrict__ wv,
                     short* __restrict__ xb, short* __restrict__ wb)
{
  const int z = blockIdx.z;
  const float* s;
  short* d;
  long nvec;
  if (z < 3) { s = (z == 0) ? q : (z == 1) ? k : v;  d = xb + (long)z * 4194304; nvec = 524288; }
  else       { s = (z == 3) ? wq : (z == 4) ? wk : wv; d = wb + (long)(z - 3) * 2097152; nvec = 262144; }
  const long stride = (long)gridDim.x * blockDim.x;
  for (long i = (long)blockIdx.x * blockDim.x + threadIdx.x; i < nvec; i += stride) {
    f32x4 a = *(const f32x4*)(s + i * 8);
    f32x4 b = *(const f32x4*)(s + i * 8 + 4);
    short8 o;
#pragma unroll
    for (int t = 0; t < 4; ++t) { o[t] = f2bf(a[t]); o[4 + t] = f2bf(b[t]); }
    *(short8*)(d + i * 8) = o;
  }
}

// K0b: single-array fp32->bf16 (for wfc, launched after attn).
__global__ void cvt1(const float* __restrict__ s, short* __restrict__ d, int nvec)
{
  const long stride = (long)gridDim.x * blockDim.x;
  for (long i = (long)blockIdx.x * blockDim.x + threadIdx.x; i < nvec; i += stride) {
    f32x4 a = *(const f32x4*)(s + i * 8);
    f32x4 b = *(const f32x4*)(s + i * 8 + 4);
    short8 o;
#pragma unroll
    for (int t = 0; t < 4; ++t) { o[t] = f2bf(a[t]); o[4 + t] = f2bf(b[t]); }
    *(short8*)(d + i * 8) = o;
  }
}

// ---------------------------------------------------------------------------
// K1: QKV projection — 256x128 tile, 8 waves (512 thr), BK=32 dbuf prefetch.
// M=8192, N=4096, K=512. z=0/1 -> (B,H,S,DK); z=2 (V) -> (B,H,DK,S).
// R22: z=2 epilogue via LDS transpose (coalesced V^T stores).
// LDS: staging As(32K)+Bs(16K) overlaid with VT[128][264] (66KB) -> 66KB,
// 2 blocks/CU (VGPR-capped at 2 anyway).
// ---------------------------------------------------------------------------
__global__ __launch_bounds__(512) void qkv_proj(
    const short* __restrict__ xb, const short* __restrict__ wb,
    short* __restrict__ Qh, short* __restrict__ Kh, short* __restrict__ Vt)
{
  __shared__ __align__(16) char smem[128 * 264 * 2];  // 67584 B
  short (*As)[256 * 32] = (short (*)[256 * 32])(smem);            // 2 x 16 KB
  short (*Bs)[128 * 32] = (short (*)[128 * 32])(smem + 32768);    // 2 x 8 KB
  const int z = blockIdx.z;
  const short* x = xb + (long)z * 4194304;
  const short* W = wb + (long)z * 2097152;
  short* out = (z == 0) ? Qh : (z == 1) ? Kh : Vt;
  const int tid = threadIdx.x;
  const int wave = tid >> 6, lane = tid & 63;
  const int quad = lane >> 4, l15 = lane & 15;
  const int mBase = blockIdx.x * 256, nBase = blockIdx.y * 128;
  const int wm = wave >> 1, wn = wave & 1;
  f32x4 acc[4][4] = {};

  auto stage = [&](int kk, int b_) {
#pragma unroll
    for (int i = 0; i < 2; ++i) {               // A: 256x32 = 1024 chunks
      int c = i * 512 + tid;
      int r = c >> 2, o = (c & 3) * 8;
      g2lds16(x + (long)(mBase + r) * 512 + kk + o, (char*)(As[b_]) + c * 16);
    }
    {                                           // B: 128x32 = 512 chunks
      int c = tid;
      int r = c >> 2, o = (c & 3) * 8;
      g2lds16(W + (long)(nBase + r) * 512 + kk + o, (char*)(Bs[b_]) + c * 16);
    }
  };
  stage(0, 0);

  for (int it = 0; it < 16; ++it) {
    const int buf = it & 1;
    stage(((it + 1) & 15) * 32, buf ^ 1);  // wrap at it=15: harmless refill
    __builtin_amdgcn_sched_barrier(0);
    asm volatile("s_waitcnt vmcnt(3)" ::: "memory");  // tile it's 3 DMAs done
    __builtin_amdgcn_s_barrier();
    __builtin_amdgcn_sched_barrier(0);
    short8 a[4], b[4];
#pragma unroll
    for (int mi = 0; mi < 4; ++mi)
      a[mi] = *(const short8*)(As[buf] + (wm * 64 + mi * 16 + l15) * 32 + quad * 8);
#pragma unroll
    for (int ni = 0; ni < 4; ++ni)
      b[ni] = *(const short8*)(Bs[buf] + (wn * 64 + ni * 16 + l15) * 32 + quad * 8);
#pragma unroll
    for (int mi = 0; mi < 4; ++mi)
#pragma unroll
      for (int ni = 0; ni < 4; ++ni)
        acc[mi][ni] = __builtin_amdgcn_mfma_f32_16x16x32_bf16(a[mi], b[ni], acc[mi][ni], 0, 0, 0);
    __builtin_amdgcn_s_barrier();  // B_end: buf reads done before next overwrite
    __builtin_amdgcn_sched_barrier(0);
  }
  asm volatile("s_waitcnt vmcnt(0)" ::: "memory");  // own wrap DMAs retired

  if (z == 2) {
    // V^T: transpose through LDS, store full 64B lines.
    __syncthreads();  // ALL waves' wrap DMAs retired -> staging LDS dead
    short* VT = (short*)smem;  // [128 d][264] (row stride 264 = 16B-aligned)
#pragma unroll
    for (int mi = 0; mi < 4; ++mi)
#pragma unroll
      for (int ni = 0; ni < 4; ++ni) {
        int dl = wn * 64 + ni * 16 + l15;
#pragma unroll
        for (int r = 0; r < 4; ++r) {
          int sl = wm * 64 + mi * 16 + quad * 4 + r;
          VT[dl * 264 + sl] = f2bf(acc[mi][ni][r]);
        }
      }
    __syncthreads();
    const int b = mBase >> 10, s0 = mBase & 1023;
    const int h = nBase >> 9, d0 = nBase & 511;
    const int dl = tid >> 2, seg = tid & 3;
    short* orow = Vt + ((long)(b * 8 + h) * 512 + d0 + dl) * 1024 + s0;
#pragma unroll
    for (int j = 0; j < 8; ++j) {
      int col = (seg + j * 4) * 8;   // 4 lanes/row cover one 64B line per j
      *(short8*)(orow + col) = *(const short8*)(VT + dl * 264 + col);
    }
  } else {
#pragma unroll
    for (int mi = 0; mi < 4; ++mi) {
#pragma unroll
      for (int ni = 0; ni < 4; ++ni) {
        int n = nBase + wn * 64 + ni * 16 + l15;
        int h = n >> 9, d = n & 511;
#pragma unroll
        for (int r = 0; r < 4; ++r) {
          int m = mBase + wm * 64 + mi * 16 + quad * 4 + r;
          int b = m >> 10, s = m & 1023;
          long idx = ((long)(b * 8 + h) * 1024 + s) * 512 + d;  // (B,H,S,DK)
          out[idx] = f2bf(acc[mi][ni][r]);
        }
      }
    }
  }
}

// ---------------------------------------------------------------------------
// K2: flash attention — 8 waves, 128 q-rows/block, K dbuf (R21 verbatim).
//  - Ks[2] XOR-swizzled (r*64+(j^(r&7))); Vs single, XOR-swizzled
//    (d*4+(j^(d&3))).
//  - Schedule/iter: stageK(kt+1)->Ks[buf^1]; stageV(kt)->Vs;
//    B1 vmcnt(8); QK^T + softmax -> Ps; B2 vmcnt(4) lgkmcnt(0);
//    vf<-Vs once, PV all 8 q-groups x own 64-d slice; B_end lgkmcnt(0).
//  - Grid 512; XCD swizzle: qt=(lin>>3)&7, bh=((lin>>6)<<3)|(lin&7).
// ---------------------------------------------------------------------------
__global__ __launch_bounds__(512, 2) void flash_attn(
    const short* __restrict__ Qh, const short* __restrict__ Kh,
    const short* __restrict__ Vt, short* __restrict__ ctx)
{
  __shared__ __align__(16) short Ks[2][32 * 512];  // 64 KB dbuf
  __shared__ __align__(16) short Vs[512 * 32];     // 32 KB
  __shared__ __align__(16) short Ps[8 * 16 * 40];  // 10 KB padded rows
  __shared__ float lred[128];
  const int tid = threadIdx.x;
  const int wave = tid >> 6, lane = tid & 63;
  const int quad = lane >> 4, l15 = lane & 15;
  const int lin = blockIdx.x;
  const int qt = (lin >> 3) & 7;
  const int bh = ((lin >> 6) << 3) | (lin & 7);
  const float C = 0.0637587234f;  // log2(e)/sqrt(512)

  // Q fragments: wave's 16 q-rows (A-operand: A[m=l15][k=quad*8+j])
  const short* qbase = Qh + ((long)bh * 1024 + qt * 128 + wave * 16 + l15) * 512 + quad * 8;
  short8 qf[16];
#pragma unroll
  for (int c = 0; c < 16; ++c) qf[c] = *(const short8*)(qbase + c * 32);

  auto stageK = [&](int kt_, int b_) {
#pragma unroll
    for (int i = 0; i < 4; ++i) {
      int c = i * 512 + tid;
      int r = c >> 6, j = (c & 63) ^ (r & 7);
      g2lds16(Kh + ((long)bh * 1024 + kt_ * 32 + r) * 512 + j * 8, (char*)(Ks[b_]) + c * 16);
    }
  };
  auto stageV = [&](int kt_) {
#pragma unroll
    for (int i = 0; i < 4; ++i) {
      int c = i * 512 + tid;
      int d = c >> 2, j = (c & 3) ^ (d & 3);
      g2lds16(Vt + ((long)bh * 512 + d) * 1024 + kt_ * 32 + j * 8, (char*)Vs + c * 16);
    }
  };
  stageK(0, 0);

  f32x4 acc[8][4] = {};               // O: [q-group g][d-tile of wave's 64-d slice]
  float l[4] = {0.f, 0.f, 0.f, 0.f};  // lane-local partial denominators (own rows)

  for (int kt = 0; kt < 32; ++kt) {
    const int buf = kt & 1;
    stageK((kt + 1) & 31, buf ^ 1);   // wrap at kt=31: harmless refill
    __builtin_amdgcn_sched_barrier(0);
    stageV(kt);
    __builtin_amdgcn_sched_barrier(0);
    // B1: K(kt) landed (K(kt+1) 4 + V(kt) 4 = 8 newer stay in flight)
    asm volatile("s_waitcnt vmcnt(8)" ::: "memory");
    __builtin_amdgcn_s_barrier();
    __builtin_amdgcn_sched_barrier(0);

    // S = Q K^T : own 16 q-rows x 32 keys
    const short* ks = Ks[buf];
    f32x4 sacc[2] = {};
#pragma unroll
    for (int nt = 0; nt < 2; ++nt)
#pragma unroll
      for (int c = 0; c < 16; ++c) {
        int row = nt * 16 + l15;
        int j = (c * 4 + quad) ^ (row & 7);
        short8 kf = *(const short8*)(ks + row * 512 + j * 8);
        sacc[nt] = __builtin_amdgcn_mfma_f32_16x16x32_bf16(qf[c], kf, sacc[nt], 0, 0, 0);
      }
    // p = exp2(s*C); lane-local partial sums; P into padded LDS
#pragma unroll
    for (int r = 0; r < 4; ++r) {
      float p0 = exp2f(sacc[0][r] * C);
      float p1 = exp2f(sacc[1][r] * C);
      Ps[wave * 640 + (quad * 4 + r) * 40 + l15]      = f2bf(p0);
      Ps[wave * 640 + (quad * 4 + r) * 40 + 16 + l15] = f2bf(p1);
      l[r] += p0 + p1;
    }
    // B2: V(kt) landed (K(kt+1) in flight); Ps visible; K reads drained
    asm volatile("s_waitcnt vmcnt(4) lgkmcnt(0)" ::: "memory");
    __builtin_amdgcn_s_barrier();
    __builtin_amdgcn_sched_barrier(0);

    // V fragments for wave's 64-d slice: read ONCE, reuse across 8 g
    short8 vf[4];
#pragma unroll
    for (int t = 0; t < 4; ++t) {
      int row = wave * 64 + t * 16 + l15;
      int j = quad ^ (row & 3);
      vf[t] = *(const short8*)(Vs + row * 32 + j * 8);
    }
    // O += P V : all 8 q-groups x wave's 64-d slice
#pragma unroll
    for (int g = 0; g < 8; ++g) {
      short8 pf = *(const short8*)(Ps + g * 640 + l15 * 40 + quad * 8);
#pragma unroll
      for (int t = 0; t < 4; ++t)
        acc[g][t] = __builtin_amdgcn_mfma_f32_16x16x32_bf16(pf, vf[t], acc[g][t], 0, 0, 0);
    }
    // B_end: this iter's LDS reads drained before next iter's DMA overwrite
    asm volatile("s_waitcnt lgkmcnt(0)" ::: "memory");
    __builtin_amdgcn_s_barrier();
    __builtin_amdgcn_sched_barrier(0);
  }
  // deferred denominator reduction (within each quad's 16 lanes)
#pragma unroll
  for (int r = 0; r < 4; ++r) {
    float t = l[r];
    t += __shfl_xor(t, 1);
    t += __shfl_xor(t, 2);
    t += __shfl_xor(t, 4);
    t += __shfl_xor(t, 8);
    l[r] = t;
  }
  if (l15 == 0) {
#pragma unroll
    for (int r = 0; r < 4; ++r) lred[wave * 16 + quad * 4 + r] = l[r];
  }
  __syncthreads();  // full drain: lred visible + wrap DMAs retired
  // epilogue: /l, store ctx (B,S,H*DK), wave's 64-d slice for all 8 q-groups
  const int b = bh >> 3, h = bh & 7;
#pragma unroll
  for (int g = 0; g < 8; ++g) {
#pragma unroll
    for (int r = 0; r < 4; ++r) {
      float inv = 1.0f / lred[g * 16 + quad * 4 + r];
      int qrow = qt * 128 + g * 16 + quad * 4 + r;
      long base = ((long)(b * 1024 + qrow)) * 4096 + h * 512 + wave * 64;
#pragma unroll
      for (int t = 0; t < 4; ++t)
        ctx[base + t * 16 + l15] = f2bf(acc[g][t][r] * inv);
    }
  }
}

// ---------------------------------------------------------------------------
// K3: fc + residual, dbuf prefetch (R21 verbatim). M=8192, N=512, K=4096.
// 128x64 tiles, grid (64,8) = 512 blocks. Per wave 64x32: acc[4][2].
// ---------------------------------------------------------------------------
__global__ void fc_gemm(
    const short* __restrict__ A, const short* __restrict__ Wb,
    const float* __restrict__ resid, float* __restrict__ Y)
{
  __shared__ __align__(16) short As[2][128 * 32];
  __shared__ __align__(16) short Bs[2][64 * 32];
  const int tid = threadIdx.x;
  const int wave = tid >> 6, lane = tid & 63;
  const int quad = lane >> 4, l15 = lane & 15;
  const int mBase = blockIdx.x * 128, nBase = blockIdx.y * 64;
  const int wm = wave >> 1, wn = wave & 1;
  const int c0 = tid, c1 = tid + 256;
  const int r0 = c0 >> 2, o0 = (c0 & 3) * 8;
  const int r1 = c1 >> 2, o1 = (c1 & 3) * 8;
  f32x4 acc[4][2] = {};

  auto stage = [&](int kk, int b_) {
    g2lds16(A + (long)(mBase + r0) * 4096 + kk + o0, (char*)(As[b_]) + c0 * 16);
    g2lds16(A + (long)(mBase + r1) * 4096 + kk + o1, (char*)(As[b_]) + c1 * 16);
    g2lds16(Wb + (long)(nBase + r0) * 4096 + kk + o0, (char*)(Bs[b_]) + c0 * 16);
  };
  stage(0, 0);

  for (int it = 0; it < 128; ++it) {
    const int buf = it & 1;
    stage(((it + 1) & 127) * 32, buf ^ 1);  // wrap at it=127: harmless refill
    __builtin_amdgcn_sched_barrier(0);
    asm volatile("s_waitcnt vmcnt(3)" ::: "memory");  // tile it's 3 DMAs done
    __builtin_amdgcn_s_barrier();
    __builtin_amdgcn_sched_barrier(0);
    short8 a[4], b[2];
#pragma unroll
    for (int mi = 0; mi < 4; ++mi)
      a[mi] = *(const short8*)(As[buf] + (wm * 64 + mi * 16 + l15) * 32 + quad * 8);
#pragma unroll
    for (int ni = 0; ni < 2; ++ni)
      b[ni] = *(const short8*)(Bs[buf] + (wn * 32 + ni * 16 + l15) * 32 + quad * 8);
#pragma unroll
    for (int mi = 0; mi < 4; ++mi)
#pragma unroll
      for (int ni = 0; ni < 2; ++ni)
        acc[mi][ni] = __builtin_amdgcn_mfma_f32_16x16x32_bf16(a[mi], b[ni], acc[mi][ni], 0, 0, 0);
    __builtin_amdgcn_s_barrier();  // B_end
    __builtin_amdgcn_sched_barrier(0);
  }
  asm volatile("s_waitcnt vmcnt(0)" ::: "memory");  // retire wrap DMAs

#pragma unroll
  for (int mi = 0; mi < 4; ++mi)
#pragma unroll
    for (int ni = 0; ni < 2; ++ni) {
      int n = nBase + wn * 32 + ni * 16 + l15;
#pragma unroll
      for (int r = 0; r < 4; ++r) {
        int m = mBase + wm * 64 + mi * 16 + quad * 4 + r;
        long idx = (long)m * 512 + n;
        Y[idx] = acc[mi][ni][r] + resid[idx];
      }
    }
}

// ---------------------------------------------------------------------------
// K4: LayerNorm (unchanged).
// ---------------------------------------------------------------------------
__global__ void layernorm(
    const float* __restrict__ Y, const float* __restrict__ gamma,
    const float* __restrict__ beta, float* __restrict__ out)
{
  const int tid = threadIdx.x;
  const int wave = tid >> 6, lane = tid & 63;
  const long row = (long)blockIdx.x * 4 + wave;
  f32x4 xa = *(const f32x4*)(Y + row * 512 + lane * 8);
  f32x4 xb = *(const f32x4*)(Y + row * 512 + lane * 8 + 4);
  float x[8];
  float s = 0.f, s2 = 0.f;
#pragma unroll
  for (int i = 0; i < 4; ++i) { x[i] = xa[i]; x[i + 4] = xb[i]; }
#pragma unroll
  for (int i = 0; i < 8; ++i) { s += x[i]; s2 += x[i] * x[i]; }
#pragma unroll
  for (int m = 1; m < 64; m <<= 1) { s += __shfl_xor(s, m); s2 += __shfl_xor(s2, m); }
  float mu = s * (1.0f / 512.0f);
  float var = s2 * (1.0f / 512.0f) - mu * mu;
  float rs = rsqrtf(var + 1e-6f);
  f32x4 oa, ob;
#pragma unroll
  for (int i = 0; i < 4; ++i) {
    oa[i] = (x[i] - mu) * rs * gamma[lane * 8 + i] + beta[lane * 8 + i];
    ob[i] = (x[i + 4] - mu) * rs * gamma[lane * 8 + 4 + i] + beta[lane * 8 + 4 + i];
  }
  *(f32x4*)(out + row * 512 + lane * 8) = oa;
  *(f32x4*)(out + row * 512 + lane * 8 + 4) = ob;
}

extern "C" void kernel_launch(void* const* d_in, const int* in_sizes, int n_in,
                              void* d_out, int out_size, void* d_ws, size_t ws_size,
                              hipStream_t stream) {
  const float* q     = (const float*)d_in[0];
  const float* k     = (const float*)d_in[1];
  const float* v     = (const float*)d_in[2];
  const float* wq    = (const float*)d_in[3];
  const float* wk    = (const float*)d_in[4];
  const float* wv    = (const float*)d_in[5];
  const float* wfc   = (const float*)d_in[6];
  const float* gamma = (const float*)d_in[7];
  const float* beta  = (const float*)d_in[8];
  float* out = (float*)d_out;
  char* ws = (char*)d_ws;
  short* Qh  = (short*)(ws);                    // [0,64M)   bf16, dead after attn
  short* Kh  = (short*)(ws + 67108864);         // [64,128M)
  short* Vt  = (short*)(ws + 134217728);        // [128,192M)
  short* ctx = (short*)(ws + 201326592);        // [192,256M) attn out (bf16)
  // cvt6 outputs live in the ctx region BEFORE attn overwrites it:
  short* xb  = (short*)(ws + 201326592);        // q/k/v bf16: 3 x 8 MB
  short* wb  = xb + 3 * 4194304;                // wq/wk/wv bf16: 3 x 4 MB
  // wfc bf16 lives in the dead-Qh region AFTER attn (Y uses [0,16M) fp32):
  short* wfcb = (short*)(ws + 16777216);        // [16,20M)
  float* Y   = (float*)(ws);                    // fp32 [0,16M), aliases dead Qh

  cvt6<<<dim3(1024, 1, 6), 256, 0, stream>>>(q, k, v, wq, wk, wv, xb, wb);
  qkv_proj<<<dim3(32, 32, 3), 512, 0, stream>>>(xb, wb, Qh, Kh, Vt);
  flash_attn<<<dim3(512), 512, 0, stream>>>(Qh, Kh, Vt, ctx);
  cvt1<<<dim3(1024), 256, 0, stream>>>(wfc, wfcb, 262144);
  fc_gemm<<<dim3(64, 8), 256, 0, stream>>>(ctx, wfcb, q, Y);
  layernorm<<<2048, 256, 0, stream>>>(Y, gamma, beta, out);
}